// Round 8
// baseline (153.068 us; speedup 1.0000x reference)
//
#include <hip/hip_runtime.h>

#define L_SEQ 4096
#define DMODEL 256
#define DH 64

typedef __attribute__((ext_vector_type(8))) __bf16 bf16x8;
typedef __attribute__((ext_vector_type(4))) __bf16 bf16v4;
typedef __attribute__((ext_vector_type(8))) __bf16 bf16v8;
typedef __attribute__((ext_vector_type(4))) float f32x4;
typedef __attribute__((ext_vector_type(8))) float f32x8;
typedef __attribute__((ext_vector_type(8))) unsigned short ushort8v;
typedef __attribute__((ext_vector_type(4))) unsigned short ushort4v;

__device__ __forceinline__ float bf2f(unsigned short h) {
  unsigned u = ((unsigned)h) << 16;
  return __builtin_bit_cast(float, u);
}
// hardware packed f32->bf16 (v_cvt_pk_bf16_f32 on gfx950)
__device__ __forceinline__ ushort4v cvt4(float a, float b, float c, float d) {
  bf16v4 h = __builtin_convertvector((f32x4){a, b, c, d}, bf16v4);
  return __builtin_bit_cast(ushort4v, h);
}
__device__ __forceinline__ ushort8v cvt8(f32x8 v) {
  bf16v8 h = __builtin_convertvector(v, bf16v8);
  return __builtin_bit_cast(ushort8v, h);
}
__device__ __forceinline__ unsigned short f2bf(float f) {
  __bf16 h = (__bf16)f;
  return __builtin_bit_cast(unsigned short, h);
}
__device__ __forceinline__ bf16x8 ld_frag(const unsigned short* p) {
  return __builtin_bit_cast(bf16x8, *(const ushort8v*)p);
}

// ---- 1. Fused transpose + QKV GEMM -> Qh [p][l][d], QhT [p][d][l] ----
// A-tile is staged straight from q [B,C,L] fp32 with lanes along L
// (256-B contiguous segments per c-row). R6's fusion failed because lanes
// were along C (stride-16KB); this fixes that, and kills the xbf round-trip.
#define KP2 136
__global__ __launch_bounds__(256) void k_qkv(const float* __restrict__ q,
                                             const float* __restrict__ w,
                                             unsigned short* __restrict__ Qh,
                                             unsigned short* __restrict__ QhT) {
  __shared__ unsigned short As[64 * KP2];
  __shared__ unsigned short Bs[64 * KP2];
  int bx = blockIdx.x;
  int mtile = bx >> 2, h = bx & 3;
  int m0 = mtile * 64;
  int b = m0 >> 12, l0 = m0 & 4095;
  int t = threadIdx.x;
  int wv = t >> 6, lane = t & 63, g = lane >> 4, ln = lane & 15;
  f32x4 acc[4] = {};
  for (int kb = 0; kb < 2; ++kb) {
    // A: As[l][c] <- q[b][kb*128+c][l0+l]; lanes along l -> coalesced
#pragma unroll
    for (int it = 0; it < 8; ++it) {
      int idx = t + it * 256;          // 0..2047
      int c = idx >> 4;                // 0..127
      int l4 = idx & 15;               // l = l4*4 .. +3
      float4 v = *(const float4*)(q + ((size_t)(b * 256 + kb * 128 + c)) * 4096 + l0 + l4 * 4);
      As[(l4 * 4 + 0) * KP2 + c] = f2bf(v.x);
      As[(l4 * 4 + 1) * KP2 + c] = f2bf(v.y);
      As[(l4 * 4 + 2) * KP2 + c] = f2bf(v.z);
      As[(l4 * 4 + 3) * KP2 + c] = f2bf(v.w);
    }
    // B: coalesced fp32 rows from w, hw-converted
#pragma unroll
    for (int it = 0; it < 4; ++it) {
      int idx = t + it * 256;
      int row = idx >> 4;
      int c8 = (idx & 15) * 8;
      const float* src = w + (size_t)(h * 64 + row) * 256 + kb * 128 + c8;
      float4 v0 = *(const float4*)(src);
      float4 v1 = *(const float4*)(src + 4);
      *(ushort8v*)(Bs + row * KP2 + c8) =
          cvt8((f32x8){v0.x, v0.y, v0.z, v0.w, v1.x, v1.y, v1.z, v1.w});
    }
    __syncthreads();
#pragma unroll
    for (int kc = 0; kc < 4; ++kc) {
      bf16x8 a = ld_frag(As + (wv * 16 + ln) * KP2 + kc * 32 + g * 8);
#pragma unroll
      for (int tn = 0; tn < 4; ++tn) {
        bf16x8 bb = ld_frag(Bs + (tn * 16 + ln) * KP2 + kc * 32 + g * 8);
        acc[tn] = __builtin_amdgcn_mfma_f32_16x16x32_bf16(a, bb, acc[tn], 0, 0, 0);
      }
    }
    __syncthreads();
  }
  size_t pbase = (size_t)(b * 4 + h);
  // epilogue: bounce tiles through LDS, then dense 16-B stores
#pragma unroll
  for (int tn = 0; tn < 4; ++tn) {
#pragma unroll
    for (int r = 0; r < 4; ++r) {
      int lrow = wv * 16 + g * 4 + r;
      int d = tn * 16 + ln;
      unsigned short bv = f2bf(acc[tn][r]);
      As[lrow * 64 + (((d >> 3) ^ (lrow & 7)) * 8) + (d & 7)] = bv;
      Bs[d * 64 + (((lrow >> 3) ^ (d & 7)) * 8) + (lrow & 7)] = bv;
    }
  }
#pragma unroll
  for (int s = 0; s < 2; ++s) {
    int flat = s * 64 + lane;
    int lrow = wv * 16 + (flat >> 3);
    int c8 = lane & 7;
    ushort8v v = *(const ushort8v*)(As + lrow * 64 + ((c8 ^ (lrow & 7)) * 8));
    *(ushort8v*)(Qh + (pbase * L_SEQ + l0 + lrow) * DH + c8 * 8) = v;
  }
  __syncthreads();
#pragma unroll
  for (int s = 0; s < 2; ++s) {
    int flat = s * 256 + t;
    int drow = flat >> 3;
    int c8 = t & 7;
    ushort8v v = *(const ushort8v*)(Bs + drow * 64 + ((c8 ^ (drow & 7)) * 8));
    *(ushort8v*)(QhT + (pbase * DH + drow) * L_SEQ + l0 + c8 * 8) = v;
  }
}

// ---- 2. flash attention, S^T = K Q^T, fixed-max softmax, key-split KSPLIT ----
// grid 8*16*KSPLIT: p = bx&7 (XCD), qsup = (bx>>3)&15, ks = bx>>7
// NOTE: __launch_bounds__(256,2) — min-waves=3 triggered scratch spill (R2-R4,
// ~190 MB/dispatch write storm). Do not re-tighten.
template <int KSPLIT>
__global__ __launch_bounds__(256, 2) void k_attn(const unsigned short* __restrict__ Qh,
                                                 const unsigned short* __restrict__ QhT,
                                                 unsigned short* __restrict__ Opart,
                                                 float* __restrict__ Lpart) {
  const int NKB = 64 / KSPLIT;
  // exp(s/8 - 16) == 2^(s*C1 + C0); v_exp_f32 is natively 2^x
  const float C1 = 0.18033688011112042f;   // 0.125 * log2(e)
  const float C0 = -23.083120654223414f;   // -16 * log2(e)
  __shared__ unsigned short Kt[64 * 64];   // [key][d], 16B chunks XOR-swizzled by row&7
  __shared__ unsigned short Vt[64 * 64];   // [d][key], same swizzle
  __shared__ unsigned short Pb[256 * 64];  // [q_local][key], same swizzle, wave-private rows
  int bx = blockIdx.x;
  int p = bx & 7;
  int u = bx >> 3;
  int qsup = u & 15, ks = u >> 4;
  int t = threadIdx.x;
  int wv = t >> 6, lane = t & 63, g = lane >> 4, ln = lane & 15;
  const unsigned short* Qp = Qh + (size_t)p * L_SEQ * DH;
  const unsigned short* QTp = QhT + (size_t)p * DH * L_SEQ;
  int q0 = qsup * 256;
  int qw = q0 + wv * 64;  // this wave's 64 q-columns

  bf16x8 aQ[4][2];
#pragma unroll
  for (int nt = 0; nt < 4; ++nt)
#pragma unroll
    for (int kc = 0; kc < 2; ++kc)
      aQ[nt][kc] = ld_frag(Qp + (size_t)(qw + nt * 16 + ln) * DH + kc * 32 + g * 8);

  f32x4 oacc[4][4] = {};
  float lacc[4] = {0.f, 0.f, 0.f, 0.f};

  int srow0 = t >> 3, scol0 = t & 7;
  int srow1 = (t + 256) >> 3, scol1 = (t + 256) & 7;
  int sdst0 = srow0 * 64 + ((scol0 ^ (srow0 & 7)) * 8);
  int sdst1 = srow1 * 64 + ((scol1 ^ (srow1 & 7)) * 8);

  ushort8v kreg0, kreg1, vreg0, vreg1;
  {
    int kbase = (ks * NKB) * 64;
    kreg0 = *(const ushort8v*)(Qp + (size_t)(kbase + srow0) * DH + scol0 * 8);
    kreg1 = *(const ushort8v*)(Qp + (size_t)(kbase + srow1) * DH + scol1 * 8);
    vreg0 = *(const ushort8v*)(QTp + (size_t)srow0 * L_SEQ + kbase + scol0 * 8);
    vreg1 = *(const ushort8v*)(QTp + (size_t)srow1 * L_SEQ + kbase + scol1 * 8);
  }

  for (int kb = 0; kb < NKB; ++kb) {
    __syncthreads();
    *(ushort8v*)(Kt + sdst0) = kreg0;
    *(ushort8v*)(Kt + sdst1) = kreg1;
    *(ushort8v*)(Vt + sdst0) = vreg0;
    *(ushort8v*)(Vt + sdst1) = vreg1;
    __syncthreads();
    if (kb + 1 < NKB) {
      int kbase = (ks * NKB + kb + 1) * 64;
      kreg0 = *(const ushort8v*)(Qp + (size_t)(kbase + srow0) * DH + scol0 * 8);
      kreg1 = *(const ushort8v*)(Qp + (size_t)(kbase + srow1) * DH + scol1 * 8);
      vreg0 = *(const ushort8v*)(QTp + (size_t)srow0 * L_SEQ + kbase + scol0 * 8);
      vreg1 = *(const ushort8v*)(QTp + (size_t)srow1 * L_SEQ + kbase + scol1 * 8);
    }
    // S^T = K Q^T
#pragma unroll
    for (int mt = 0; mt < 4; ++mt) {
      int krow = mt * 16 + ln;
      bf16x8 aK0 = ld_frag(Kt + krow * 64 + (((0 * 4 + g) ^ (ln & 7)) * 8));
      bf16x8 aK1 = ld_frag(Kt + krow * 64 + (((1 * 4 + g) ^ (ln & 7)) * 8));
      f32x4 s[4] = {};
#pragma unroll
      for (int nt = 0; nt < 4; ++nt) {
        s[nt] = __builtin_amdgcn_mfma_f32_16x16x32_bf16(aK0, aQ[nt][0], s[nt], 0, 0, 0);
        s[nt] = __builtin_amdgcn_mfma_f32_16x16x32_bf16(aK1, aQ[nt][1], s[nt], 0, 0, 0);
      }
#pragma unroll
      for (int nt = 0; nt < 4; ++nt) {
        float p0 = exp2f(fmaf(s[nt][0], C1, C0));
        float p1 = exp2f(fmaf(s[nt][1], C1, C0));
        float p2 = exp2f(fmaf(s[nt][2], C1, C0));
        float p3 = exp2f(fmaf(s[nt][3], C1, C0));
        lacc[nt] += (p0 + p1) + (p2 + p3);
        ushort4v pk = cvt4(p0, p1, p2, p3);
        int row = wv * 64 + nt * 16 + ln;
        int addr = row * 64 + (((2 * mt + (g >> 1)) ^ (ln & 7)) * 8) + (g & 1) * 4;
        *(ushort4v*)(Pb + addr) = pk;
      }
    }
    // O += P V
#pragma unroll
    for (int kc = 0; kc < 2; ++kc) {
      bf16x8 bV[4];
#pragma unroll
      for (int tn = 0; tn < 4; ++tn)
        bV[tn] = ld_frag(Vt + (tn * 16 + ln) * 64 + (((kc * 4 + g) ^ (ln & 7)) * 8));
#pragma unroll
      for (int mq = 0; mq < 4; ++mq) {
        bf16x8 aP = ld_frag(Pb + (wv * 64 + mq * 16 + ln) * 64 + (((kc * 4 + g) ^ (ln & 7)) * 8));
#pragma unroll
        for (int tn = 0; tn < 4; ++tn)
          oacc[mq][tn] = __builtin_amdgcn_mfma_f32_16x16x32_bf16(aP, bV[tn], oacc[mq][tn], 0, 0, 0);
      }
    }
  }
#pragma unroll
  for (int nt = 0; nt < 4; ++nt) {
    lacc[nt] += __shfl_xor(lacc[nt], 16, 64);
    lacc[nt] += __shfl_xor(lacc[nt], 32, 64);
  }
  size_t pq = (size_t)(ks * 8 + p) * L_SEQ;
  if (g == 0) {
#pragma unroll
    for (int nt = 0; nt < 4; ++nt)
      __builtin_nontemporal_store(lacc[nt], &Lpart[pq + qw + nt * 16 + ln]);
  }
#pragma unroll
  for (int mq = 0; mq < 4; ++mq) {
#pragma unroll
    for (int r = 0; r < 4; ++r) {
      int row = wv * 64 + mq * 16 + g * 4 + r;
#pragma unroll
      for (int tn = 0; tn < 4; ++tn) {
        int d = tn * 16 + ln;
        Pb[row * 64 + (((d >> 3) ^ (row & 7)) * 8) + (d & 7)] = f2bf(oacc[mq][tn][r]);
      }
    }
  }
#pragma unroll
  for (int s = 0; s < 8; ++s) {
    int flat = s * 64 + lane;
    int row = wv * 64 + (flat >> 3);
    int c8 = lane & 7;
    ushort8v v = *(const ushort8v*)(Pb + row * 64 + ((c8 ^ (row & 7)) * 8));
    __builtin_nontemporal_store(v, (ushort8v*)(Opart + (pq + q0 + row) * DH + c8 * 8));
  }
}

// ---- 3. FC GEMM (fused ks-merge) + bias + residual + LN. 16-row tiles,
// grid 512 -> 2 wg/CU. ----
#define CP 72
template <int KSPLIT>
__global__ __launch_bounds__(256) void k_fc(const unsigned short* __restrict__ Opart,
                                            const float* __restrict__ Lpart,
                                            const float* __restrict__ fcw,
                                            const float* __restrict__ qres,
                                            const float* __restrict__ fcb,
                                            const float* __restrict__ lng,
                                            const float* __restrict__ lnb,
                                            float* __restrict__ out) {
  __shared__ unsigned short As[16 * CP];
  __shared__ unsigned short Bs[256 * CP];
  __shared__ float invL[4][16];
  __shared__ float redS[4][16], redQ[4][16], muA[16], rsA[16];
  int bx = blockIdx.x;
  int m0 = bx * 16;
  int b = m0 >> 12, lpart = m0 & 4095;
  int t = threadIdx.x;
  int wv = t >> 6, lane = t & 63, g = lane >> 4, ln = lane & 15;
  // precompute 1/L once per (head,row)
  if (t < 64) {
    int row = t >> 2, hh = t & 3;
    int p = b * 4 + hh;
    float lsum = 0.f;
#pragma unroll
    for (int ksp = 0; ksp < KSPLIT; ++ksp)
      lsum += Lpart[(size_t)(ksp * 8 + p) * L_SEQ + lpart + row];
    invL[hh][row] = 1.0f / lsum;
  }
  __syncthreads();
  f32x4 acc[4] = {};
  for (int kb = 0; kb < 4; ++kb) {   // kb == head index for A-staging
    if (t < 128) {
      int row = t >> 3, c0 = (t & 7) * 8;
      int qrow = lpart + row;
      int p = b * 4 + kb;
      float inv = invL[kb][row];
      float a8[8] = {0.f, 0.f, 0.f, 0.f, 0.f, 0.f, 0.f, 0.f};
#pragma unroll
      for (int ksp = 0; ksp < KSPLIT; ++ksp) {
        ushort8v v = __builtin_nontemporal_load(
            (const ushort8v*)(Opart + ((size_t)(ksp * 8 + p) * L_SEQ + qrow) * DH + c0));
#pragma unroll
        for (int j = 0; j < 8; ++j) a8[j] += bf2f(v[j]);
      }
      *(ushort8v*)(As + row * CP + c0) =
          cvt8((f32x8){a8[0] * inv, a8[1] * inv, a8[2] * inv, a8[3] * inv,
                       a8[4] * inv, a8[5] * inv, a8[6] * inv, a8[7] * inv});
    }
#pragma unroll
    for (int it = 0; it < 8; ++it) {
      int idx = t + it * 256;
      int row = idx >> 3, c0 = (idx & 7) * 8;
      const float* src = fcw + (size_t)row * 256 + kb * 64 + c0;
      float4 v0 = *(const float4*)(src);
      float4 v1 = *(const float4*)(src + 4);
      *(ushort8v*)(Bs + row * CP + c0) =
          cvt8((f32x8){v0.x, v0.y, v0.z, v0.w, v1.x, v1.y, v1.z, v1.w});
    }
    __syncthreads();
#pragma unroll
    for (int kc = 0; kc < 2; ++kc) {
      bf16x8 a = ld_frag(As + ln * CP + kc * 32 + g * 8);
#pragma unroll
      for (int tn = 0; tn < 4; ++tn) {
        bf16x8 bb = ld_frag(Bs + (wv * 64 + tn * 16 + ln) * CP + kc * 32 + g * 8);
        acc[tn] = __builtin_amdgcn_mfma_f32_16x16x32_bf16(a, bb, acc[tn], 0, 0, 0);
      }
    }
    __syncthreads();
  }
  float fb[4], lg[4], lb[4];
#pragma unroll
  for (int tn = 0; tn < 4; ++tn) {
    int o = wv * 64 + tn * 16 + ln;
    fb[tn] = fcb[o]; lg[tn] = lng[o]; lb[tn] = lnb[o];
  }
  float ps[4] = {0.f, 0.f, 0.f, 0.f}, pq2[4] = {0.f, 0.f, 0.f, 0.f};
#pragma unroll
  for (int tn = 0; tn < 4; ++tn) {
    int o = wv * 64 + tn * 16 + ln;
    float4 res = *(const float4*)(qres + ((size_t)(b * 256 + o)) * 4096 + lpart + g * 4);
    float rv[4] = {res.x, res.y, res.z, res.w};
#pragma unroll
    for (int r = 0; r < 4; ++r) {
      float v = acc[tn][r] + fb[tn] + rv[r];
      acc[tn][r] = v;
      ps[r] += v;
      pq2[r] += v * v;
    }
  }
#pragma unroll
  for (int r = 0; r < 4; ++r) {
    float s = ps[r], q2 = pq2[r];
#pragma unroll
    for (int off = 1; off < 16; off <<= 1) {
      s += __shfl_xor(s, off, 64);
      q2 += __shfl_xor(q2, off, 64);
    }
    if (ln == 0) {
      int row = g * 4 + r;
      redS[wv][row] = s;
      redQ[wv][row] = q2;
    }
  }
  __syncthreads();
  if (t < 16) {
    float s = redS[0][t] + redS[1][t] + redS[2][t] + redS[3][t];
    float q2 = redQ[0][t] + redQ[1][t] + redQ[2][t] + redQ[3][t];
    float mu = s * (1.f / 256.f);
    float var = q2 * (1.f / 256.f) - mu * mu;
    muA[t] = mu;
    rsA[t] = rsqrtf(var + 1e-5f);
  }
  __syncthreads();
#pragma unroll
  for (int r = 0; r < 4; ++r) {
    int row = g * 4 + r;
    float mu = muA[row], rs = rsA[row];
#pragma unroll
    for (int tn = 0; tn < 4; ++tn) {
      int o = wv * 64 + tn * 16 + ln;
      out[(size_t)(m0 + row) * 256 + o] = (acc[tn][r] - mu) * rs * lg[tn] + lb[tn];
    }
  }
}

extern "C" void kernel_launch(void* const* d_in, const int* in_sizes, int n_in,
                              void* d_out, int out_size, void* d_ws, size_t ws_size,
                              hipStream_t stream) {
  const float* q = (const float*)d_in[0];
  const float* w_qkv = (const float*)d_in[1];
  const float* fc_w = (const float*)d_in[2];
  const float* fc_b = (const float*)d_in[3];
  const float* ln_g = (const float*)d_in[4];
  const float* ln_b = (const float*)d_in[5];
  float* out = (float*)d_out;

  unsigned short* Qh = (unsigned short*)d_ws;          // [p][l][d]   4 MB
  unsigned short* QhT = Qh + 2097152;                  // [p][d][l]   4 MB
  float* Lpart = (float*)(QhT + 2097152);              // [ks][p][q]  0.5 MB (1 MB reserved)
  unsigned short* Opart = (unsigned short*)((char*)Lpart + 1048576);  // [ks][p][q][d] 16.7 MB
  // total ws use: ~25.7 MB (ks4)

  k_qkv<<<dim3(512), dim3(256), 0, stream>>>(q, w_qkv, Qh, QhT);
  k_attn<4><<<dim3(512), dim3(256), 0, stream>>>(Qh, QhT, Opart, Lpart);
  k_fc<4><<<dim3(512), dim3(256), 0, stream>>>(Opart, Lpart, fc_w, q, fc_b, ln_g, ln_b, out);
}

// Round 9
// 141.768 us; speedup vs baseline: 1.0797x; 1.0797x over previous
//
#include <hip/hip_runtime.h>

#define L_SEQ 4096
#define DMODEL 256
#define DH 64

typedef __attribute__((ext_vector_type(8))) __bf16 bf16x8;
typedef __attribute__((ext_vector_type(4))) __bf16 bf16v4;
typedef __attribute__((ext_vector_type(8))) __bf16 bf16v8;
typedef __attribute__((ext_vector_type(4))) float f32x4;
typedef __attribute__((ext_vector_type(8))) float f32x8;
typedef __attribute__((ext_vector_type(8))) unsigned short ushort8v;
typedef __attribute__((ext_vector_type(4))) unsigned short ushort4v;

__device__ __forceinline__ float bf2f(unsigned short h) {
  unsigned u = ((unsigned)h) << 16;
  return __builtin_bit_cast(float, u);
}
// hardware packed f32->bf16 (v_cvt_pk_bf16_f32 on gfx950)
__device__ __forceinline__ ushort4v cvt4(float a, float b, float c, float d) {
  bf16v4 h = __builtin_convertvector((f32x4){a, b, c, d}, bf16v4);
  return __builtin_bit_cast(ushort4v, h);
}
__device__ __forceinline__ ushort8v cvt8(f32x8 v) {
  bf16v8 h = __builtin_convertvector(v, bf16v8);
  return __builtin_bit_cast(ushort8v, h);
}
__device__ __forceinline__ unsigned short f2bf(float f) {
  __bf16 h = (__bf16)f;
  return __builtin_bit_cast(unsigned short, h);
}
__device__ __forceinline__ bf16x8 ld_frag(const unsigned short* p) {
  return __builtin_bit_cast(bf16x8, *(const ushort8v*)p);
}

// ---- 1. q [B,C,L] fp32 -> xbf [B*L, C] bf16 (coalesced LDS-tiled transpose).
// Lesson R6/R8: fusing this into k_qkv costs more in LDS scalar writes /
// uncoalesced loads than the extra launch. Keep it separate.
__global__ __launch_bounds__(256) void k_transpose(const float* __restrict__ q,
                                                   unsigned short* __restrict__ xbf) {
  __shared__ float T[64 * 65];
  int bx = blockIdx.x;
  int b = bx >> 8, rest = bx & 255;
  int ct = rest >> 6, lt = rest & 63;
  int t = threadIdx.x;
#pragma unroll
  for (int it = 0; it < 4; ++it) {
    int i = (t >> 4) + it * 16;
    int j0 = (t & 15) * 4;
    float4 v = *(const float4*)(q + ((size_t)(b * 256 + ct * 64 + i)) * 4096 + lt * 64 + j0);
    T[i * 65 + j0 + 0] = v.x;
    T[i * 65 + j0 + 1] = v.y;
    T[i * 65 + j0 + 2] = v.z;
    T[i * 65 + j0 + 3] = v.w;
  }
  __syncthreads();
#pragma unroll
  for (int it = 0; it < 2; ++it) {
    int l = (t >> 3) + it * 32;
    int c0 = (t & 7) * 8;
    f32x8 v;
#pragma unroll
    for (int k = 0; k < 8; ++k) v[k] = T[(c0 + k) * 65 + l];
    *(ushort8v*)(xbf + ((size_t)(b * 4096 + lt * 64 + l)) * 256 + ct * 64 + c0) = cvt8(v);
  }
}

// ---- 2. QKV GEMM (A from bf16 xbf, B from fp32 w) -> Qh [p][l][d], QhT [p][d][l] ----
#define KP2 136
__global__ __launch_bounds__(256) void k_qkv(const unsigned short* __restrict__ xbf,
                                             const float* __restrict__ w,
                                             unsigned short* __restrict__ Qh,
                                             unsigned short* __restrict__ QhT) {
  __shared__ unsigned short As[64 * KP2];
  __shared__ unsigned short Bs[64 * KP2];
  int bx = blockIdx.x;
  int mtile = bx >> 2, h = bx & 3;
  int m0 = mtile * 64;
  int b = m0 >> 12, l0 = m0 & 4095;
  int t = threadIdx.x;
  int wv = t >> 6, lane = t & 63, g = lane >> 4, ln = lane & 15;
  f32x4 acc[4] = {};
  for (int kb = 0; kb < 2; ++kb) {
    // A: coalesced bf16 rows from xbf
#pragma unroll
    for (int it = 0; it < 4; ++it) {
      int idx = t + it * 256;
      int row = idx >> 4;
      int c0 = (idx & 15) * 8;
      *(ushort8v*)(As + row * KP2 + c0) =
          *(const ushort8v*)(xbf + (size_t)(m0 + row) * 256 + kb * 128 + c0);
    }
    // B: coalesced fp32 rows from w, hw-converted
#pragma unroll
    for (int it = 0; it < 4; ++it) {
      int idx = t + it * 256;
      int row = idx >> 4;
      int c8 = (idx & 15) * 8;
      const float* src = w + (size_t)(h * 64 + row) * 256 + kb * 128 + c8;
      float4 v0 = *(const float4*)(src);
      float4 v1 = *(const float4*)(src + 4);
      *(ushort8v*)(Bs + row * KP2 + c8) =
          cvt8((f32x8){v0.x, v0.y, v0.z, v0.w, v1.x, v1.y, v1.z, v1.w});
    }
    __syncthreads();
#pragma unroll
    for (int kc = 0; kc < 4; ++kc) {
      bf16x8 a = ld_frag(As + (wv * 16 + ln) * KP2 + kc * 32 + g * 8);
#pragma unroll
      for (int tn = 0; tn < 4; ++tn) {
        bf16x8 bb = ld_frag(Bs + (tn * 16 + ln) * KP2 + kc * 32 + g * 8);
        acc[tn] = __builtin_amdgcn_mfma_f32_16x16x32_bf16(a, bb, acc[tn], 0, 0, 0);
      }
    }
    __syncthreads();
  }
  size_t pbase = (size_t)(b * 4 + h);
  // epilogue: bounce tiles through LDS, then dense 16-B stores
#pragma unroll
  for (int tn = 0; tn < 4; ++tn) {
#pragma unroll
    for (int r = 0; r < 4; ++r) {
      int lrow = wv * 16 + g * 4 + r;
      int d = tn * 16 + ln;
      unsigned short bv = f2bf(acc[tn][r]);
      As[lrow * 64 + (((d >> 3) ^ (lrow & 7)) * 8) + (d & 7)] = bv;
      Bs[d * 64 + (((lrow >> 3) ^ (d & 7)) * 8) + (lrow & 7)] = bv;
    }
  }
#pragma unroll
  for (int s = 0; s < 2; ++s) {
    int flat = s * 64 + lane;
    int lrow = wv * 16 + (flat >> 3);
    int c8 = lane & 7;
    ushort8v v = *(const ushort8v*)(As + lrow * 64 + ((c8 ^ (lrow & 7)) * 8));
    *(ushort8v*)(Qh + (pbase * L_SEQ + l0 + lrow) * DH + c8 * 8) = v;
  }
  __syncthreads();
#pragma unroll
  for (int s = 0; s < 2; ++s) {
    int flat = s * 256 + t;
    int drow = flat >> 3;
    int c8 = t & 7;
    ushort8v v = *(const ushort8v*)(Bs + drow * 64 + ((c8 ^ (drow & 7)) * 8));
    *(ushort8v*)(QhT + (pbase * DH + drow) * L_SEQ + l0 + c8 * 8) = v;
  }
}

// ---- 3. flash attention, S^T = K Q^T, fixed-max softmax, key-split 4 ----
// grid 512: p = bx&7 (XCD), qsup = (bx>>3)&15, ks = bx>>7
// L (softmax denominator) computed by MFMA with B=ones instead of VALU adds.
// NOTE: __launch_bounds__(256,2) — min-waves=3 triggered scratch spill (R2-R4,
// ~190 MB/dispatch write storm). Do not re-tighten. __expf only (exp2f = slow
// libm path, cost 5 µs in R8).
template <int KSPLIT>
__global__ __launch_bounds__(256, 2) void k_attn(const unsigned short* __restrict__ Qh,
                                                 const unsigned short* __restrict__ QhT,
                                                 unsigned short* __restrict__ Opart,
                                                 float* __restrict__ Lpart) {
  const int NKB = 64 / KSPLIT;
  __shared__ unsigned short Kt[64 * 64];   // [key][d], 16B chunks XOR-swizzled by row&7
  __shared__ unsigned short Vt[64 * 64];   // [d][key], same swizzle
  __shared__ unsigned short Pb[256 * 64];  // [q_local][key], same swizzle, wave-private rows
  int bx = blockIdx.x;
  int p = bx & 7;
  int u = bx >> 3;
  int qsup = u & 15, ks = u >> 4;
  int t = threadIdx.x;
  int wv = t >> 6, lane = t & 63, g = lane >> 4, ln = lane & 15;
  const unsigned short* Qp = Qh + (size_t)p * L_SEQ * DH;
  const unsigned short* QTp = QhT + (size_t)p * DH * L_SEQ;
  int q0 = qsup * 256;
  int qw = q0 + wv * 64;  // this wave's 64 q-columns

  bf16x8 aQ[4][2];
#pragma unroll
  for (int nt = 0; nt < 4; ++nt)
#pragma unroll
    for (int kc = 0; kc < 2; ++kc)
      aQ[nt][kc] = ld_frag(Qp + (size_t)(qw + nt * 16 + ln) * DH + kc * 32 + g * 8);

  // all-ones bf16x8 for MFMA row-sum (L accumulation)
  const ushort8v ones_u = {0x3F80, 0x3F80, 0x3F80, 0x3F80, 0x3F80, 0x3F80, 0x3F80, 0x3F80};
  const bf16x8 bOnes = __builtin_bit_cast(bf16x8, ones_u);

  f32x4 oacc[4][4] = {};
  f32x4 oaccL[4] = {};   // L row-sums via MFMA (all 16 cols identical)

  int srow0 = t >> 3, scol0 = t & 7;
  int srow1 = (t + 256) >> 3, scol1 = (t + 256) & 7;
  int sdst0 = srow0 * 64 + ((scol0 ^ (srow0 & 7)) * 8);
  int sdst1 = srow1 * 64 + ((scol1 ^ (srow1 & 7)) * 8);

  ushort8v kreg0, kreg1, vreg0, vreg1;
  {
    int kbase = (ks * NKB) * 64;
    kreg0 = *(const ushort8v*)(Qp + (size_t)(kbase + srow0) * DH + scol0 * 8);
    kreg1 = *(const ushort8v*)(Qp + (size_t)(kbase + srow1) * DH + scol1 * 8);
    vreg0 = *(const ushort8v*)(QTp + (size_t)srow0 * L_SEQ + kbase + scol0 * 8);
    vreg1 = *(const ushort8v*)(QTp + (size_t)srow1 * L_SEQ + kbase + scol1 * 8);
  }

  for (int kb = 0; kb < NKB; ++kb) {
    __syncthreads();
    *(ushort8v*)(Kt + sdst0) = kreg0;
    *(ushort8v*)(Kt + sdst1) = kreg1;
    *(ushort8v*)(Vt + sdst0) = vreg0;
    *(ushort8v*)(Vt + sdst1) = vreg1;
    __syncthreads();
    if (kb + 1 < NKB) {
      int kbase = (ks * NKB + kb + 1) * 64;
      kreg0 = *(const ushort8v*)(Qp + (size_t)(kbase + srow0) * DH + scol0 * 8);
      kreg1 = *(const ushort8v*)(Qp + (size_t)(kbase + srow1) * DH + scol1 * 8);
      vreg0 = *(const ushort8v*)(QTp + (size_t)srow0 * L_SEQ + kbase + scol0 * 8);
      vreg1 = *(const ushort8v*)(QTp + (size_t)srow1 * L_SEQ + kbase + scol1 * 8);
    }
    // S^T = K Q^T
#pragma unroll
    for (int mt = 0; mt < 4; ++mt) {
      int krow = mt * 16 + ln;
      bf16x8 aK0 = ld_frag(Kt + krow * 64 + (((0 * 4 + g) ^ (ln & 7)) * 8));
      bf16x8 aK1 = ld_frag(Kt + krow * 64 + (((1 * 4 + g) ^ (ln & 7)) * 8));
      f32x4 s[4] = {};
#pragma unroll
      for (int nt = 0; nt < 4; ++nt) {
        s[nt] = __builtin_amdgcn_mfma_f32_16x16x32_bf16(aK0, aQ[nt][0], s[nt], 0, 0, 0);
        s[nt] = __builtin_amdgcn_mfma_f32_16x16x32_bf16(aK1, aQ[nt][1], s[nt], 0, 0, 0);
      }
#pragma unroll
      for (int nt = 0; nt < 4; ++nt) {
        float p0 = __expf(fmaf(s[nt][0], 0.125f, -16.0f));
        float p1 = __expf(fmaf(s[nt][1], 0.125f, -16.0f));
        float p2 = __expf(fmaf(s[nt][2], 0.125f, -16.0f));
        float p3 = __expf(fmaf(s[nt][3], 0.125f, -16.0f));
        ushort4v pk = cvt4(p0, p1, p2, p3);
        int row = wv * 64 + nt * 16 + ln;
        int addr = row * 64 + (((2 * mt + (g >> 1)) ^ (ln & 7)) * 8) + (g & 1) * 4;
        *(ushort4v*)(Pb + addr) = pk;
      }
    }
    // O += P V ; L += P 1 (row-sum on the MFMA pipe)
#pragma unroll
    for (int kc = 0; kc < 2; ++kc) {
      bf16x8 bV[4];
#pragma unroll
      for (int tn = 0; tn < 4; ++tn)
        bV[tn] = ld_frag(Vt + (tn * 16 + ln) * 64 + (((kc * 4 + g) ^ (ln & 7)) * 8));
#pragma unroll
      for (int mq = 0; mq < 4; ++mq) {
        bf16x8 aP = ld_frag(Pb + (wv * 64 + mq * 16 + ln) * 64 + (((kc * 4 + g) ^ (ln & 7)) * 8));
#pragma unroll
        for (int tn = 0; tn < 4; ++tn)
          oacc[mq][tn] = __builtin_amdgcn_mfma_f32_16x16x32_bf16(aP, bV[tn], oacc[mq][tn], 0, 0, 0);
        oaccL[mq] = __builtin_amdgcn_mfma_f32_16x16x32_bf16(aP, bOnes, oaccL[mq], 0, 0, 0);
      }
    }
  }
  size_t pq = (size_t)(ks * 8 + p) * L_SEQ;
  // L: C[q][*] all columns identical; quad g holds rows g*4+r of each mq tile
  if (ln == 0) {
#pragma unroll
    for (int mq = 0; mq < 4; ++mq)
#pragma unroll
      for (int r = 0; r < 4; ++r)
        __builtin_nontemporal_store(oaccL[mq][r],
                                    &Lpart[pq + qw + mq * 16 + g * 4 + r]);
  }
  // epilogue: bounce O through Pb (wave-private rows), dense nt stores
#pragma unroll
  for (int mq = 0; mq < 4; ++mq) {
#pragma unroll
    for (int r = 0; r < 4; ++r) {
      int row = wv * 64 + mq * 16 + g * 4 + r;
#pragma unroll
      for (int tn = 0; tn < 4; ++tn) {
        int d = tn * 16 + ln;
        Pb[row * 64 + (((d >> 3) ^ (row & 7)) * 8) + (d & 7)] = f2bf(oacc[mq][tn][r]);
      }
    }
  }
#pragma unroll
  for (int s = 0; s < 8; ++s) {
    int flat = s * 64 + lane;
    int row = wv * 64 + (flat >> 3);
    int c8 = lane & 7;
    ushort8v v = *(const ushort8v*)(Pb + row * 64 + ((c8 ^ (row & 7)) * 8));
    __builtin_nontemporal_store(v, (ushort8v*)(Opart + (pq + q0 + row) * DH + c8 * 8));
  }
}

// ---- 4. FC GEMM (fused ks-merge) + bias + residual + LN. 16-row tiles,
// grid 512 -> 2 wg/CU. ----
#define CP 72
template <int KSPLIT>
__global__ __launch_bounds__(256) void k_fc(const unsigned short* __restrict__ Opart,
                                            const float* __restrict__ Lpart,
                                            const float* __restrict__ fcw,
                                            const float* __restrict__ qres,
                                            const float* __restrict__ fcb,
                                            const float* __restrict__ lng,
                                            const float* __restrict__ lnb,
                                            float* __restrict__ out) {
  __shared__ unsigned short As[16 * CP];
  __shared__ unsigned short Bs[256 * CP];
  __shared__ float invL[4][16];
  __shared__ float redS[4][16], redQ[4][16], muA[16], rsA[16];
  int bx = blockIdx.x;
  int m0 = bx * 16;
  int b = m0 >> 12, lpart = m0 & 4095;
  int t = threadIdx.x;
  int wv = t >> 6, lane = t & 63, g = lane >> 4, ln = lane & 15;
  // precompute 1/L once per (head,row)
  if (t < 64) {
    int row = t >> 2, hh = t & 3;
    int p = b * 4 + hh;
    float lsum = 0.f;
#pragma unroll
    for (int ksp = 0; ksp < KSPLIT; ++ksp)
      lsum += Lpart[(size_t)(ksp * 8 + p) * L_SEQ + lpart + row];
    invL[hh][row] = 1.0f / lsum;
  }
  __syncthreads();
  f32x4 acc[4] = {};
  for (int kb = 0; kb < 4; ++kb) {   // kb == head index for A-staging
    if (t < 128) {
      int row = t >> 3, c0 = (t & 7) * 8;
      int qrow = lpart + row;
      int p = b * 4 + kb;
      float inv = invL[kb][row];
      float a8[8] = {0.f, 0.f, 0.f, 0.f, 0.f, 0.f, 0.f, 0.f};
#pragma unroll
      for (int ksp = 0; ksp < KSPLIT; ++ksp) {
        ushort8v v = __builtin_nontemporal_load(
            (const ushort8v*)(Opart + ((size_t)(ksp * 8 + p) * L_SEQ + qrow) * DH + c0));
#pragma unroll
        for (int j = 0; j < 8; ++j) a8[j] += bf2f(v[j]);
      }
      *(ushort8v*)(As + row * CP + c0) =
          cvt8((f32x8){a8[0] * inv, a8[1] * inv, a8[2] * inv, a8[3] * inv,
                       a8[4] * inv, a8[5] * inv, a8[6] * inv, a8[7] * inv});
    }
#pragma unroll
    for (int it = 0; it < 8; ++it) {
      int idx = t + it * 256;
      int row = idx >> 3, c0 = (idx & 7) * 8;
      const float* src = fcw + (size_t)row * 256 + kb * 64 + c0;
      float4 v0 = *(const float4*)(src);
      float4 v1 = *(const float4*)(src + 4);
      *(ushort8v*)(Bs + row * CP + c0) =
          cvt8((f32x8){v0.x, v0.y, v0.z, v0.w, v1.x, v1.y, v1.z, v1.w});
    }
    __syncthreads();
#pragma unroll
    for (int kc = 0; kc < 2; ++kc) {
      bf16x8 a = ld_frag(As + ln * CP + kc * 32 + g * 8);
#pragma unroll
      for (int tn = 0; tn < 4; ++tn) {
        bf16x8 bb = ld_frag(Bs + (wv * 64 + tn * 16 + ln) * CP + kc * 32 + g * 8);
        acc[tn] = __builtin_amdgcn_mfma_f32_16x16x32_bf16(a, bb, acc[tn], 0, 0, 0);
      }
    }
    __syncthreads();
  }
  float fb[4], lg[4], lb[4];
#pragma unroll
  for (int tn = 0; tn < 4; ++tn) {
    int o = wv * 64 + tn * 16 + ln;
    fb[tn] = fcb[o]; lg[tn] = lng[o]; lb[tn] = lnb[o];
  }
  float ps[4] = {0.f, 0.f, 0.f, 0.f}, pq2[4] = {0.f, 0.f, 0.f, 0.f};
#pragma unroll
  for (int tn = 0; tn < 4; ++tn) {
    int o = wv * 64 + tn * 16 + ln;
    float4 res = *(const float4*)(qres + ((size_t)(b * 256 + o)) * 4096 + lpart + g * 4);
    float rv[4] = {res.x, res.y, res.z, res.w};
#pragma unroll
    for (int r = 0; r < 4; ++r) {
      float v = acc[tn][r] + fb[tn] + rv[r];
      acc[tn][r] = v;
      ps[r] += v;
      pq2[r] += v * v;
    }
  }
#pragma unroll
  for (int r = 0; r < 4; ++r) {
    float s = ps[r], q2 = pq2[r];
#pragma unroll
    for (int off = 1; off < 16; off <<= 1) {
      s += __shfl_xor(s, off, 64);
      q2 += __shfl_xor(q2, off, 64);
    }
    if (ln == 0) {
      int row = g * 4 + r;
      redS[wv][row] = s;
      redQ[wv][row] = q2;
    }
  }
  __syncthreads();
  if (t < 16) {
    float s = redS[0][t] + redS[1][t] + redS[2][t] + redS[3][t];
    float q2 = redQ[0][t] + redQ[1][t] + redQ[2][t] + redQ[3][t];
    float mu = s * (1.f / 256.f);
    float var = q2 * (1.f / 256.f) - mu * mu;
    muA[t] = mu;
    rsA[t] = rsqrtf(var + 1e-5f);
  }
  __syncthreads();
#pragma unroll
  for (int r = 0; r < 4; ++r) {
    int row = g * 4 + r;
    float mu = muA[row], rs = rsA[row];
#pragma unroll
    for (int tn = 0; tn < 4; ++tn) {
      int o = wv * 64 + tn * 16 + ln;
      out[(size_t)(m0 + row) * 256 + o] = (acc[tn][r] - mu) * rs * lg[tn] + lb[tn];
    }
  }
}

extern "C" void kernel_launch(void* const* d_in, const int* in_sizes, int n_in,
                              void* d_out, int out_size, void* d_ws, size_t ws_size,
                              hipStream_t stream) {
  const float* q = (const float*)d_in[0];
  const float* w_qkv = (const float*)d_in[1];
  const float* fc_w = (const float*)d_in[2];
  const float* fc_b = (const float*)d_in[3];
  const float* ln_g = (const float*)d_in[4];
  const float* ln_b = (const float*)d_in[5];
  float* out = (float*)d_out;

  unsigned short* Qh = (unsigned short*)d_ws;          // [p][l][d]   4 MB
  unsigned short* QhT = Qh + 2097152;                  // [p][d][l]   4 MB
  float* Lpart = (float*)(QhT + 2097152);              // [ks][p][q]  0.5 MB (1 MB reserved)
  unsigned short* Opart = (unsigned short*)((char*)Lpart + 1048576);  // [ks][p][q][d] 16.7 MB
  unsigned short* xbf = Opart;   // xbf aliases Opart: dead before k_attn writes
  // total ws use: ~25.7 MB

  k_transpose<<<dim3(512), dim3(256), 0, stream>>>(q, xbf);
  k_qkv<<<dim3(512), dim3(256), 0, stream>>>(xbf, w_qkv, Qh, QhT);
  k_attn<4><<<dim3(512), dim3(256), 0, stream>>>(Qh, QhT, Opart, Lpart);
  k_fc<4><<<dim3(512), dim3(256), 0, stream>>>(Opart, Lpart, fc_w, q, fc_b, ln_g, ln_b, out);
}